// Round 4
// baseline (827.337 us; speedup 1.0000x reference)
//
#include <hip/hip_runtime.h>

#define S_TOT 32768
#define C_IN 192
#define NB 2
#define NH 8
#define DH 64
#define ATT_SCALE 0.125f

// workspace layout (float offsets)
#define G_OFF   0
#define G_SZ    (NB * C_IN * C_IN)        // 73728
#define T_OFF   (G_OFF + G_SZ)
#define T_SZ    (NB * 512 * C_IN)         // 196608
#define M_OFF   (T_OFF + T_SZ)
#define M_SZ    (NB * 512 * C_IN)         // 196608
#define WBF_OFF (M_OFF + M_SZ)            // bf16 W: NB*192*192 ushorts = 36864 floats
#define WBF_SZ  (NB * C_IN * C_IN / 2)

typedef __attribute__((ext_vector_type(8))) short short8;
typedef __attribute__((ext_vector_type(4))) float f32x4;

__device__ inline unsigned short f2bf(float f) {   // RNE, no NaN concern here
    unsigned int u = __float_as_uint(f);
    u += 0x7fffu + ((u >> 16) & 1u);
    return (unsigned short)(u >> 16);
}

// ---------------- Gram: G[b] = X_b * X_b^T, read-once, fp32 (precision-critical) ----------------
// grid (128, NB), block 512. K-slice 256 (8 chunks of 32). micro 6x12:
// rows tyy+32*rr (broadcast scalar reads), cols tx*12+cc (3x ds_read_b128).
#define GR_CH 8
#define GR_BK 32
__global__ __launch_bounds__(512, 2) void gram_kernel(const float* __restrict__ x,
                                                      float* __restrict__ G) {
    int b     = blockIdx.y;
    int kbase = blockIdx.x * (GR_CH * GR_BK);

    __shared__ float Ls[GR_BK][196];

    int tid = threadIdx.x;
    int tx  = tid & 15;       // col group: cols tx*12 + cc
    int tyy = tid >> 4;       // rows tyy + 32*rr

    const float* xb = x + (size_t)b * C_IN * S_TOT;

    int lc[3], lkq[3];
#pragma unroll
    for (int q = 0; q < 3; q++) { int id = tid + 512 * q; lc[q] = id >> 3; lkq[q] = id & 7; }

    float acc[6][12] = {};
    float4 pf[3];

#pragma unroll
    for (int q = 0; q < 3; q++)
        pf[q] = *(const float4*)(xb + (size_t)lc[q] * S_TOT + kbase + lkq[q] * 4);

    for (int ch = 0; ch < GR_CH; ++ch) {
        __syncthreads();
#pragma unroll
        for (int q = 0; q < 3; q++) {
            Ls[lkq[q] * 4 + 0][lc[q]] = pf[q].x;
            Ls[lkq[q] * 4 + 1][lc[q]] = pf[q].y;
            Ls[lkq[q] * 4 + 2][lc[q]] = pf[q].z;
            Ls[lkq[q] * 4 + 3][lc[q]] = pf[q].w;
        }
        __syncthreads();
        if (ch + 1 < GR_CH) {
            int k0 = kbase + (ch + 1) * GR_BK;
#pragma unroll
            for (int q = 0; q < 3; q++)
                pf[q] = *(const float4*)(xb + (size_t)lc[q] * S_TOT + k0 + lkq[q] * 4);
        }
#pragma unroll
        for (int kk = 0; kk < GR_BK; ++kk) {
            float a[6];
#pragma unroll
            for (int rr = 0; rr < 6; ++rr) a[rr] = Ls[kk][tyy + 32 * rr];
            float4 c0 = *(const float4*)&Ls[kk][tx * 12];
            float4 c1 = *(const float4*)&Ls[kk][tx * 12 + 4];
            float4 c2 = *(const float4*)&Ls[kk][tx * 12 + 8];
            float bb[12] = { c0.x, c0.y, c0.z, c0.w, c1.x, c1.y, c1.z, c1.w, c2.x, c2.y, c2.z, c2.w };
#pragma unroll
            for (int rr = 0; rr < 6; ++rr)
#pragma unroll
                for (int cc = 0; cc < 12; ++cc)
                    acc[rr][cc] = fmaf(a[rr], bb[cc], acc[rr][cc]);
        }
    }

    float* Gb = G + b * C_IN * C_IN;
#pragma unroll
    for (int rr = 0; rr < 6; ++rr)
#pragma unroll
        for (int cc = 0; cc < 12; ++cc)
            atomicAdd(&Gb[(tyy + 32 * rr) * C_IN + tx * 12 + cc], acc[rr][cc]);
}

// ---------------- generic 64x64-tile GEMM (fp32): C[b] = A[b] (MxK) * B[b] (KxN) ----------------
__global__ __launch_bounds__(256) void gemm64_kernel(const float* __restrict__ A,
                                                     const float* __restrict__ B,
                                                     float* __restrict__ C,
                                                     int K, int N,
                                                     long aStride, long bStride, long cStride) {
    int mi0 = blockIdx.x * 64;
    int nj0 = blockIdx.y * 64;
    int b   = blockIdx.z;

    __shared__ float As[16][68];
    __shared__ float Bs[16][68];

    int tid = threadIdx.x;
    int tx = tid & 15, ty = tid >> 4;
    int lrow = tid >> 2, lk = (tid & 3) * 4;
    int ldk = tid >> 4, ldn = (tid & 15) * 4;

    const float* Ab = A + b * aStride;
    const float* Bb = B + b * bStride;

    float acc[4][4] = {};

    for (int k0 = 0; k0 < K; k0 += 16) {
        float4 av = *(const float4*)(Ab + (size_t)(mi0 + lrow) * K + k0 + lk);
        float4 bv = *(const float4*)(Bb + (size_t)(k0 + ldk) * N + nj0 + ldn);
        __syncthreads();
        As[lk + 0][lrow] = av.x; As[lk + 1][lrow] = av.y;
        As[lk + 2][lrow] = av.z; As[lk + 3][lrow] = av.w;
        *(float4*)&Bs[ldk][ldn] = bv;
        __syncthreads();
#pragma unroll
        for (int kk = 0; kk < 16; kk++) {
            float4 a = *(const float4*)&As[kk][ty * 4];
            float4 bb = *(const float4*)&Bs[kk][tx * 4];
            acc[0][0] += a.x * bb.x; acc[0][1] += a.x * bb.y; acc[0][2] += a.x * bb.z; acc[0][3] += a.x * bb.w;
            acc[1][0] += a.y * bb.x; acc[1][1] += a.y * bb.y; acc[1][2] += a.y * bb.z; acc[1][3] += a.y * bb.w;
            acc[2][0] += a.z * bb.x; acc[2][1] += a.z * bb.y; acc[2][2] += a.z * bb.z; acc[2][3] += a.z * bb.w;
            acc[3][0] += a.w * bb.x; acc[3][1] += a.w * bb.y; acc[3][2] += a.w * bb.z; acc[3][3] += a.w * bb.w;
        }
    }

    float* Cb = C + b * cStride;
#pragma unroll
    for (int r = 0; r < 4; r++) {
        float4 v = { acc[r][0], acc[r][1], acc[r][2], acc[r][3] };
        *(float4*)(Cb + (size_t)(mi0 + ty * 4 + r) * N + nj0 + tx * 4) = v;
    }
}

// ---------------- fused: sim = T_h wk_h^T * SCALE -> softmax -> M_h = attn * wv_h (fp32) ----------------
__global__ __launch_bounds__(256) void simsoftm_kernel(const float* __restrict__ T,
                                                       const float* __restrict__ wk,
                                                       const float* __restrict__ wv,
                                                       float* __restrict__ M) {
    int b = blockIdx.x, h = blockIdx.y;

    __shared__ float As[16][68];
    __shared__ float Bs[16][68];
    __shared__ float At[64][68];

    int tid = threadIdx.x;
    int tx = tid & 15, ty = tid >> 4;
    int lrow = tid >> 2, lk = (tid & 3) * 4;
    int ldk = tid >> 4, ldn = (tid & 15) * 4;

    const float* Th  = T + (size_t)b * 512 * C_IN + (size_t)(h * 64) * C_IN;
    const float* wkh = wk + (size_t)(h * 64) * C_IN;
    const float* wvh = wv + (size_t)(h * 64) * C_IN;

    float acc[4][4] = {};
    for (int k0 = 0; k0 < C_IN; k0 += 16) {
        float4 av = *(const float4*)(Th  + (size_t)lrow * C_IN + k0 + lk);
        float4 bv = *(const float4*)(wkh + (size_t)lrow * C_IN + k0 + lk);
        __syncthreads();
        As[lk + 0][lrow] = av.x; As[lk + 1][lrow] = av.y;
        As[lk + 2][lrow] = av.z; As[lk + 3][lrow] = av.w;
        Bs[lk + 0][lrow] = bv.x; Bs[lk + 1][lrow] = bv.y;
        Bs[lk + 2][lrow] = bv.z; Bs[lk + 3][lrow] = bv.w;
        __syncthreads();
#pragma unroll
        for (int kk = 0; kk < 16; kk++) {
            float4 a = *(const float4*)&As[kk][ty * 4];
            float4 bb = *(const float4*)&Bs[kk][tx * 4];
            acc[0][0] += a.x * bb.x; acc[0][1] += a.x * bb.y; acc[0][2] += a.x * bb.z; acc[0][3] += a.x * bb.w;
            acc[1][0] += a.y * bb.x; acc[1][1] += a.y * bb.y; acc[1][2] += a.y * bb.z; acc[1][3] += a.y * bb.w;
            acc[2][0] += a.z * bb.x; acc[2][1] += a.z * bb.y; acc[2][2] += a.z * bb.z; acc[2][3] += a.z * bb.w;
            acc[3][0] += a.w * bb.x; acc[3][1] += a.w * bb.y; acc[3][2] += a.w * bb.z; acc[3][3] += a.w * bb.w;
        }
    }

#pragma unroll
    for (int r = 0; r < 4; r++) {
        float s0 = acc[r][0] * ATT_SCALE, s1 = acc[r][1] * ATT_SCALE;
        float s2 = acc[r][2] * ATT_SCALE, s3 = acc[r][3] * ATT_SCALE;
        float mx = fmaxf(fmaxf(s0, s1), fmaxf(s2, s3));
        mx = fmaxf(mx, __shfl_xor(mx, 1));
        mx = fmaxf(mx, __shfl_xor(mx, 2));
        mx = fmaxf(mx, __shfl_xor(mx, 4));
        mx = fmaxf(mx, __shfl_xor(mx, 8));
        float e0 = __expf(s0 - mx), e1 = __expf(s1 - mx);
        float e2 = __expf(s2 - mx), e3 = __expf(s3 - mx);
        float sum = (e0 + e1) + (e2 + e3);
        sum += __shfl_xor(sum, 1);
        sum += __shfl_xor(sum, 2);
        sum += __shfl_xor(sum, 4);
        sum += __shfl_xor(sum, 8);
        float inv = 1.0f / sum;
        At[tx * 4 + 0][ty * 4 + r] = e0 * inv;
        At[tx * 4 + 1][ty * 4 + r] = e1 * inv;
        At[tx * 4 + 2][ty * 4 + r] = e2 * inv;
        At[tx * 4 + 3][ty * 4 + r] = e3 * inv;
    }

    float* Mb = M + (size_t)b * 512 * C_IN + (size_t)(h * 64) * C_IN;
    for (int nj = 0; nj < C_IN; nj += 64) {
        float acc2[4][4] = {};
        for (int j0 = 0; j0 < 64; j0 += 16) {
            float4 bv = *(const float4*)(wvh + (size_t)(j0 + ldk) * C_IN + nj + ldn);
            __syncthreads();
            *(float4*)&Bs[ldk][ldn] = bv;
            __syncthreads();
#pragma unroll
            for (int kk = 0; kk < 16; kk++) {
                float4 a = *(const float4*)&At[j0 + kk][ty * 4];
                float4 bb = *(const float4*)&Bs[kk][tx * 4];
                acc2[0][0] += a.x * bb.x; acc2[0][1] += a.x * bb.y; acc2[0][2] += a.x * bb.z; acc2[0][3] += a.x * bb.w;
                acc2[1][0] += a.y * bb.x; acc2[1][1] += a.y * bb.y; acc2[1][2] += a.y * bb.z; acc2[1][3] += a.y * bb.w;
                acc2[2][0] += a.z * bb.x; acc2[2][1] += a.z * bb.y; acc2[2][2] += a.z * bb.z; acc2[2][3] += a.z * bb.w;
                acc2[3][0] += a.w * bb.x; acc2[3][1] += a.w * bb.y; acc2[3][2] += a.w * bb.z; acc2[3][3] += a.w * bb.w;
            }
        }
#pragma unroll
        for (int r = 0; r < 4; r++) {
            float4 v = { acc2[r][0], acc2[r][1], acc2[r][2], acc2[r][3] };
            *(float4*)(Mb + (size_t)(ty * 4 + r) * C_IN + nj + tx * 4) = v;
        }
    }
}

// ---------------- W[b][o][c] = sum_c5 wo[o][c5] * M[b][c5][c], output bf16 ----------------
__global__ __launch_bounds__(256) void w_kernel(const float* __restrict__ wo,
                                                const float* __restrict__ M,
                                                unsigned short* __restrict__ Wbf) {
    int b = blockIdx.x;
    int o0 = blockIdx.y * 16;
    const float* Mb = M + b * 512 * C_IN;
    unsigned short* Wb = Wbf + b * C_IN * C_IN;
    int tid = threadIdx.x;
    for (int idx = tid; idx < 16 * C_IN; idx += 256) {
        int ol = idx / C_IN, c = idx - ol * C_IN;
        const float* wor = wo + (o0 + ol) * 512;
        float s0 = 0, s1 = 0, s2 = 0, s3 = 0;
        for (int c5 = 0; c5 < 512; c5 += 4) {
            s0 += wor[c5 + 0] * Mb[(c5 + 0) * C_IN + c];
            s1 += wor[c5 + 1] * Mb[(c5 + 1) * C_IN + c];
            s2 += wor[c5 + 2] * Mb[(c5 + 2) * C_IN + c];
            s3 += wor[c5 + 3] * Mb[(c5 + 3) * C_IN + c];
        }
        Wb[(o0 + ol) * C_IN + c] = f2bf((s0 + s1) + (s2 + s3));
    }
}

// ---------------- out[b][o][s] = sum_c W[b][o][c] * x[b][c][s] + bo[o], bf16 MFMA ----------------
// grid (128, NB), block 512 (8 waves). Block: full M=192, n-slice 256, K=192 in 6 chunks of 32.
// Wave tile: 96m x 64n = 6x4 16x16 tiles. A-frags direct from global Wbf (L2-hot).
// Xs: [256 n][40 ushort] (stride 40 -> 2-way bank conflicts = free, 16B-aligned rows).
__global__ __launch_bounds__(512) void final_kernel(const float* __restrict__ x,
                                                    const unsigned short* __restrict__ Wbf,
                                                    const float* __restrict__ bo,
                                                    float* __restrict__ out) {
    int n0 = blockIdx.x * 256;
    int b  = blockIdx.y;

    __shared__ unsigned short Xs[256 * 40];

    int tid  = threadIdx.x;
    int wave = tid >> 6;
    int lane = tid & 63;
    int wm   = (wave & 1) * 96;      // 2 m-groups of 96
    int wn   = (wave >> 1) * 64;     // 4 n-groups of 64
    int lm   = lane & 15, quad = lane >> 4;

    int sn  = tid & 255;             // staging n (0..255)
    int skh = (tid >> 8) * 16;       // staging k-half: 0 or 16

    const float* xsrc = x + (size_t)b * C_IN * S_TOT + n0 + sn;
    const unsigned short* Wb = Wbf + b * C_IN * C_IN;

    f32x4 acc[6][4];
#pragma unroll
    for (int mt = 0; mt < 6; mt++)
#pragma unroll
        for (int nt = 0; nt < 4; nt++) acc[mt][nt] = (f32x4){0.f, 0.f, 0.f, 0.f};

    float pf[16];
#pragma unroll
    for (int j = 0; j < 16; j++) pf[j] = xsrc[(size_t)(skh + j) * S_TOT];

    for (int kc = 0; kc < 6; ++kc) {
        int k0 = kc * 32;
        __syncthreads();
        {
            short8 v0, v1;
#pragma unroll
            for (int j = 0; j < 8; j++) { v0[j] = (short)f2bf(pf[j]); v1[j] = (short)f2bf(pf[8 + j]); }
            *(short8*)&Xs[sn * 40 + skh + 0] = v0;
            *(short8*)&Xs[sn * 40 + skh + 8] = v1;
        }
        __syncthreads();
        if (kc + 1 < 6) {
            int kn = k0 + 32;
#pragma unroll
            for (int j = 0; j < 16; j++) pf[j] = xsrc[(size_t)(kn + skh + j) * S_TOT];
        }

        short8 afr[6];
#pragma unroll
        for (int mt = 0; mt < 6; mt++)
            afr[mt] = *(const short8*)(Wb + (size_t)(wm + mt * 16 + lm) * C_IN + k0 + quad * 8);
#pragma unroll
        for (int nt = 0; nt < 4; nt++) {
            short8 bfr = *(const short8*)&Xs[(wn + nt * 16 + lm) * 40 + quad * 8];
#pragma unroll
            for (int mt = 0; mt < 6; mt++)
                acc[mt][nt] = __builtin_amdgcn_mfma_f32_16x16x32_bf16(afr[mt], bfr, acc[mt][nt], 0, 0, 0);
        }
    }

#pragma unroll
    for (int mt = 0; mt < 6; mt++) {
#pragma unroll
        for (int r = 0; r < 4; r++) {
            int m = wm + mt * 16 + quad * 4 + r;
            float bias = bo[m];
            float* op = out + ((size_t)b * C_IN + m) * S_TOT + n0;
#pragma unroll
            for (int nt = 0; nt < 4; nt++)
                op[wn + nt * 16 + lm] = acc[mt][nt][r] + bias;
        }
    }
}

extern "C" void kernel_launch(void* const* d_in, const int* in_sizes, int n_in,
                              void* d_out, int out_size, void* d_ws, size_t ws_size,
                              hipStream_t stream) {
    const float* x  = (const float*)d_in[0];
    const float* wq = (const float*)d_in[1];
    const float* wk = (const float*)d_in[2];
    const float* wv = (const float*)d_in[3];
    const float* wo = (const float*)d_in[4];
    const float* bo = (const float*)d_in[5];
    float* out = (float*)d_out;
    float* ws  = (float*)d_ws;

    float* gG = ws + G_OFF;
    float* gT = ws + T_OFF;
    float* gM = ws + M_OFF;
    unsigned short* gWbf = (unsigned short*)(ws + WBF_OFF);

    hipMemsetAsync(gG, 0, G_SZ * sizeof(float), stream);
    gram_kernel<<<dim3(128, NB), 512, 0, stream>>>(x, gG);

    // T[b] = wq (512x192) * G_b (192x192)
    gemm64_kernel<<<dim3(8, 3, NB), 256, 0, stream>>>(
        wq, gG, gT, C_IN, C_IN, 0L, (long)(C_IN * C_IN), (long)(512 * C_IN));

    simsoftm_kernel<<<dim3(NB, NH), 256, 0, stream>>>(gT, wk, wv, gM);

    // W[b] = wo (192x512) * M_b (512x192), bf16 out
    w_kernel<<<dim3(NB, 12), 256, 0, stream>>>(wo, gM, gWbf);

    final_kernel<<<dim3(128, NB), 512, 0, stream>>>(x, gWbf, bo, out);
}

// Round 5
// 387.865 us; speedup vs baseline: 2.1331x; 2.1331x over previous
//
#include <hip/hip_runtime.h>

#define S_TOT 32768
#define C_IN 192
#define NB 2
#define NH 8
#define DH 64
#define ATT_SCALE 0.125f

// workspace layout (float offsets)
#define G_OFF   0
#define G_SZ    (NB * C_IN * C_IN)        // 73728
#define T_OFF   (G_OFF + G_SZ)
#define T_SZ    (NB * 512 * C_IN)         // 196608
#define M_OFF   (T_OFF + T_SZ)
#define M_SZ    (NB * 512 * C_IN)         // 196608
#define WBF_OFF (M_OFF + M_SZ)
#define WBF_SZ  (NB * C_IN * C_IN / 2)    // 36864 (bf16 stored as half-floats)
#define P_OFF   (WBF_OFF + WBF_SZ)        // 503808
#define NSLICE  128
#define P_SZ    (NB * NSLICE * C_IN * C_IN)   // 9437184 floats = 37.75 MB

typedef __attribute__((ext_vector_type(8))) short short8;
typedef __attribute__((ext_vector_type(4))) float f32x4;

__device__ inline unsigned short f2bf(float f) {   // RNE
    unsigned int u = __float_as_uint(f);
    u += 0x7fffu + ((u >> 16) & 1u);
    return (unsigned short)(u >> 16);
}

// ---------------- Gram main (partial-write path): P[b][slice] = X-slice * X-slice^T ----------------
// grid (128, NB), block 512. K-slice 256 (8 chunks of 32). micro 6x12:
// rows tyy+32*rr (broadcast scalar LDS reads), cols tx*12+cc (3x ds_read_b128, 2-way=free).
// NO atomics: plain dwordx4 stores to P. (R4 lesson: scattered atomics -> 295MB L2 writeback.)
#define GR_CH 8
#define GR_BK 32
__global__ __launch_bounds__(512, 2) void gram_partial(const float* __restrict__ x,
                                                       float* __restrict__ P) {
    int b     = blockIdx.y;
    int slice = blockIdx.x;
    int kbase = slice * (GR_CH * GR_BK);

    __shared__ float Ls[GR_BK][196];

    int tid = threadIdx.x;
    int tx  = tid & 15;       // cols tx*12 + cc
    int tyy = tid >> 4;       // rows tyy + 32*rr

    const float* xb = x + (size_t)b * C_IN * S_TOT;

    int lc[3], lkq[3];
#pragma unroll
    for (int q = 0; q < 3; q++) { int id = tid + 512 * q; lc[q] = id >> 3; lkq[q] = id & 7; }

    float acc[6][12] = {};
    float4 pf[3];

#pragma unroll
    for (int q = 0; q < 3; q++)
        pf[q] = *(const float4*)(xb + (size_t)lc[q] * S_TOT + kbase + lkq[q] * 4);

    for (int ch = 0; ch < GR_CH; ++ch) {
        __syncthreads();
#pragma unroll
        for (int q = 0; q < 3; q++) {
            Ls[lkq[q] * 4 + 0][lc[q]] = pf[q].x;
            Ls[lkq[q] * 4 + 1][lc[q]] = pf[q].y;
            Ls[lkq[q] * 4 + 2][lc[q]] = pf[q].z;
            Ls[lkq[q] * 4 + 3][lc[q]] = pf[q].w;
        }
        __syncthreads();
        if (ch + 1 < GR_CH) {
            int k0 = kbase + (ch + 1) * GR_BK;
#pragma unroll
            for (int q = 0; q < 3; q++)
                pf[q] = *(const float4*)(xb + (size_t)lc[q] * S_TOT + k0 + lkq[q] * 4);
        }
#pragma unroll
        for (int kk = 0; kk < GR_BK; ++kk) {
            float a[6];
#pragma unroll
            for (int rr = 0; rr < 6; ++rr) a[rr] = Ls[kk][tyy + 32 * rr];
            float4 c0 = *(const float4*)&Ls[kk][tx * 12];
            float4 c1 = *(const float4*)&Ls[kk][tx * 12 + 4];
            float4 c2 = *(const float4*)&Ls[kk][tx * 12 + 8];
            float bb[12] = { c0.x, c0.y, c0.z, c0.w, c1.x, c1.y, c1.z, c1.w, c2.x, c2.y, c2.z, c2.w };
#pragma unroll
            for (int rr = 0; rr < 6; ++rr)
#pragma unroll
                for (int cc = 0; cc < 12; ++cc)
                    acc[rr][cc] = fmaf(a[rr], bb[cc], acc[rr][cc]);
        }
    }

    float* Pb = P + ((size_t)(b * NSLICE + slice)) * (C_IN * C_IN);
#pragma unroll
    for (int rr = 0; rr < 6; ++rr) {
        float* row = Pb + (tyy + 32 * rr) * C_IN + tx * 12;
#pragma unroll
        for (int u = 0; u < 3; u++) {
            float4 v = { acc[rr][u * 4 + 0], acc[rr][u * 4 + 1], acc[rr][u * 4 + 2], acc[rr][u * 4 + 3] };
            *(float4*)(row + u * 4) = v;
        }
    }
}

// ---------------- Gram reduce: G[b] += sum_s P[b][s]  (grid (36, 4, NB), block 256) ----------------
__global__ __launch_bounds__(256) void gram_reduce(const float* __restrict__ P,
                                                   float* __restrict__ G) {
    int b  = blockIdx.z;
    int s0 = blockIdx.y * (NSLICE / 4);
    int idx4 = (blockIdx.x * 256 + threadIdx.x) * 4;   // 36*256*4 = 36864

    const float* Pb = P + ((size_t)(b * NSLICE + s0)) * (C_IN * C_IN) + idx4;
    float4 acc = {0.f, 0.f, 0.f, 0.f};
#pragma unroll 4
    for (int s = 0; s < NSLICE / 4; ++s) {
        float4 v = *(const float4*)(Pb + (size_t)s * (C_IN * C_IN));
        acc.x += v.x; acc.y += v.y; acc.z += v.z; acc.w += v.w;
    }
    float* g = G + (size_t)b * C_IN * C_IN + idx4;
    atomicAdd(g + 0, acc.x);
    atomicAdd(g + 1, acc.y);
    atomicAdd(g + 2, acc.z);
    atomicAdd(g + 3, acc.w);
}

// ---------------- Gram fallback (atomic path, R3-proven): used if ws too small ----------------
__global__ __launch_bounds__(512, 2) void gram_atomic(const float* __restrict__ x,
                                                      float* __restrict__ G) {
    int b     = blockIdx.y;
    int kbase = blockIdx.x * (GR_CH * GR_BK);

    __shared__ float Ls[GR_BK][196];

    int tid = threadIdx.x;
    int tx  = tid & 15;       // cols tx + 16*cc  (coalesced atomics)
    int tyy = tid >> 4;

    const float* xb = x + (size_t)b * C_IN * S_TOT;

    int lc[3], lkq[3];
#pragma unroll
    for (int q = 0; q < 3; q++) { int id = tid + 512 * q; lc[q] = id >> 3; lkq[q] = id & 7; }

    float acc[6][12] = {};
    float4 pf[3];

#pragma unroll
    for (int q = 0; q < 3; q++)
        pf[q] = *(const float4*)(xb + (size_t)lc[q] * S_TOT + kbase + lkq[q] * 4);

    for (int ch = 0; ch < GR_CH; ++ch) {
        __syncthreads();
#pragma unroll
        for (int q = 0; q < 3; q++) {
            Ls[lkq[q] * 4 + 0][lc[q]] = pf[q].x;
            Ls[lkq[q] * 4 + 1][lc[q]] = pf[q].y;
            Ls[lkq[q] * 4 + 2][lc[q]] = pf[q].z;
            Ls[lkq[q] * 4 + 3][lc[q]] = pf[q].w;
        }
        __syncthreads();
        if (ch + 1 < GR_CH) {
            int k0 = kbase + (ch + 1) * GR_BK;
#pragma unroll
            for (int q = 0; q < 3; q++)
                pf[q] = *(const float4*)(xb + (size_t)lc[q] * S_TOT + k0 + lkq[q] * 4);
        }
#pragma unroll
        for (int kk = 0; kk < GR_BK; ++kk) {
            float a[6], bb[12];
#pragma unroll
            for (int rr = 0; rr < 6; ++rr)  a[rr] = Ls[kk][tyy + 32 * rr];
#pragma unroll
            for (int cc = 0; cc < 12; ++cc) bb[cc] = Ls[kk][tx + 16 * cc];
#pragma unroll
            for (int rr = 0; rr < 6; ++rr)
#pragma unroll
                for (int cc = 0; cc < 12; ++cc)
                    acc[rr][cc] = fmaf(a[rr], bb[cc], acc[rr][cc]);
        }
    }

    float* Gb = G + b * C_IN * C_IN;
#pragma unroll
    for (int rr = 0; rr < 6; ++rr)
#pragma unroll
        for (int cc = 0; cc < 12; ++cc)
            atomicAdd(&Gb[(tyy + 32 * rr) * C_IN + tx + 16 * cc], acc[rr][cc]);
}

// ---------------- generic 64x64-tile GEMM (fp32) ----------------
__global__ __launch_bounds__(256) void gemm64_kernel(const float* __restrict__ A,
                                                     const float* __restrict__ B,
                                                     float* __restrict__ C,
                                                     int K, int N,
                                                     long aStride, long bStride, long cStride) {
    int mi0 = blockIdx.x * 64;
    int nj0 = blockIdx.y * 64;
    int b   = blockIdx.z;

    __shared__ float As[16][68];
    __shared__ float Bs[16][68];

    int tid = threadIdx.x;
    int tx = tid & 15, ty = tid >> 4;
    int lrow = tid >> 2, lk = (tid & 3) * 4;
    int ldk = tid >> 4, ldn = (tid & 15) * 4;

    const float* Ab = A + b * aStride;
    const float* Bb = B + b * bStride;

    float acc[4][4] = {};

    for (int k0 = 0; k0 < K; k0 += 16) {
        float4 av = *(const float4*)(Ab + (size_t)(mi0 + lrow) * K + k0 + lk);
        float4 bv = *(const float4*)(Bb + (size_t)(k0 + ldk) * N + nj0 + ldn);
        __syncthreads();
        As[lk + 0][lrow] = av.x; As[lk + 1][lrow] = av.y;
        As[lk + 2][lrow] = av.z; As[lk + 3][lrow] = av.w;
        *(float4*)&Bs[ldk][ldn] = bv;
        __syncthreads();
#pragma unroll
        for (int kk = 0; kk < 16; kk++) {
            float4 a = *(const float4*)&As[kk][ty * 4];
            float4 bb = *(const float4*)&Bs[kk][tx * 4];
            acc[0][0] += a.x * bb.x; acc[0][1] += a.x * bb.y; acc[0][2] += a.x * bb.z; acc[0][3] += a.x * bb.w;
            acc[1][0] += a.y * bb.x; acc[1][1] += a.y * bb.y; acc[1][2] += a.y * bb.z; acc[1][3] += a.y * bb.w;
            acc[2][0] += a.z * bb.x; acc[2][1] += a.z * bb.y; acc[2][2] += a.z * bb.z; acc[2][3] += a.z * bb.w;
            acc[3][0] += a.w * bb.x; acc[3][1] += a.w * bb.y; acc[3][2] += a.w * bb.z; acc[3][3] += a.w * bb.w;
        }
    }

    float* Cb = C + b * cStride;
#pragma unroll
    for (int r = 0; r < 4; r++) {
        float4 v = { acc[r][0], acc[r][1], acc[r][2], acc[r][3] };
        *(float4*)(Cb + (size_t)(mi0 + ty * 4 + r) * N + nj0 + tx * 4) = v;
    }
}

// ---------------- fused: sim = T_h wk_h^T * SCALE -> softmax -> M_h = attn * wv_h (fp32) ----------------
__global__ __launch_bounds__(256) void simsoftm_kernel(const float* __restrict__ T,
                                                       const float* __restrict__ wk,
                                                       const float* __restrict__ wv,
                                                       float* __restrict__ M) {
    int b = blockIdx.x, h = blockIdx.y;

    __shared__ float As[16][68];
    __shared__ float Bs[16][68];
    __shared__ float At[64][68];

    int tid = threadIdx.x;
    int tx = tid & 15, ty = tid >> 4;
    int lrow = tid >> 2, lk = (tid & 3) * 4;
    int ldk = tid >> 4, ldn = (tid & 15) * 4;

    const float* Th  = T + (size_t)b * 512 * C_IN + (size_t)(h * 64) * C_IN;
    const float* wkh = wk + (size_t)(h * 64) * C_IN;
    const float* wvh = wv + (size_t)(h * 64) * C_IN;

    float acc[4][4] = {};
    for (int k0 = 0; k0 < C_IN; k0 += 16) {
        float4 av = *(const float4*)(Th  + (size_t)lrow * C_IN + k0 + lk);
        float4 bv = *(const float4*)(wkh + (size_t)lrow * C_IN + k0 + lk);
        __syncthreads();
        As[lk + 0][lrow] = av.x; As[lk + 1][lrow] = av.y;
        As[lk + 2][lrow] = av.z; As[lk + 3][lrow] = av.w;
        Bs[lk + 0][lrow] = bv.x; Bs[lk + 1][lrow] = bv.y;
        Bs[lk + 2][lrow] = bv.z; Bs[lk + 3][lrow] = bv.w;
        __syncthreads();
#pragma unroll
        for (int kk = 0; kk < 16; kk++) {
            float4 a = *(const float4*)&As[kk][ty * 4];
            float4 bb = *(const float4*)&Bs[kk][tx * 4];
            acc[0][0] += a.x * bb.x; acc[0][1] += a.x * bb.y; acc[0][2] += a.x * bb.z; acc[0][3] += a.x * bb.w;
            acc[1][0] += a.y * bb.x; acc[1][1] += a.y * bb.y; acc[1][2] += a.y * bb.z; acc[1][3] += a.y * bb.w;
            acc[2][0] += a.z * bb.x; acc[2][1] += a.z * bb.y; acc[2][2] += a.z * bb.z; acc[2][3] += a.z * bb.w;
            acc[3][0] += a.w * bb.x; acc[3][1] += a.w * bb.y; acc[3][2] += a.w * bb.z; acc[3][3] += a.w * bb.w;
        }
    }

#pragma unroll
    for (int r = 0; r < 4; r++) {
        float s0 = acc[r][0] * ATT_SCALE, s1 = acc[r][1] * ATT_SCALE;
        float s2 = acc[r][2] * ATT_SCALE, s3 = acc[r][3] * ATT_SCALE;
        float mx = fmaxf(fmaxf(s0, s1), fmaxf(s2, s3));
        mx = fmaxf(mx, __shfl_xor(mx, 1));
        mx = fmaxf(mx, __shfl_xor(mx, 2));
        mx = fmaxf(mx, __shfl_xor(mx, 4));
        mx = fmaxf(mx, __shfl_xor(mx, 8));
        float e0 = __expf(s0 - mx), e1 = __expf(s1 - mx);
        float e2 = __expf(s2 - mx), e3 = __expf(s3 - mx);
        float sum = (e0 + e1) + (e2 + e3);
        sum += __shfl_xor(sum, 1);
        sum += __shfl_xor(sum, 2);
        sum += __shfl_xor(sum, 4);
        sum += __shfl_xor(sum, 8);
        float inv = 1.0f / sum;
        At[tx * 4 + 0][ty * 4 + r] = e0 * inv;
        At[tx * 4 + 1][ty * 4 + r] = e1 * inv;
        At[tx * 4 + 2][ty * 4 + r] = e2 * inv;
        At[tx * 4 + 3][ty * 4 + r] = e3 * inv;
    }

    float* Mb = M + (size_t)b * 512 * C_IN + (size_t)(h * 64) * C_IN;
    for (int nj = 0; nj < C_IN; nj += 64) {
        float acc2[4][4] = {};
        for (int j0 = 0; j0 < 64; j0 += 16) {
            float4 bv = *(const float4*)(wvh + (size_t)(j0 + ldk) * C_IN + nj + ldn);
            __syncthreads();
            *(float4*)&Bs[ldk][ldn] = bv;
            __syncthreads();
#pragma unroll
            for (int kk = 0; kk < 16; kk++) {
                float4 a = *(const float4*)&At[j0 + kk][ty * 4];
                float4 bb = *(const float4*)&Bs[kk][tx * 4];
                acc2[0][0] += a.x * bb.x; acc2[0][1] += a.x * bb.y; acc2[0][2] += a.x * bb.z; acc2[0][3] += a.x * bb.w;
                acc2[1][0] += a.y * bb.x; acc2[1][1] += a.y * bb.y; acc2[1][2] += a.y * bb.z; acc2[1][3] += a.y * bb.w;
                acc2[2][0] += a.z * bb.x; acc2[2][1] += a.z * bb.y; acc2[2][2] += a.z * bb.z; acc2[2][3] += a.z * bb.w;
                acc2[3][0] += a.w * bb.x; acc2[3][1] += a.w * bb.y; acc2[3][2] += a.w * bb.z; acc2[3][3] += a.w * bb.w;
            }
        }
#pragma unroll
        for (int r = 0; r < 4; r++) {
            float4 v = { acc2[r][0], acc2[r][1], acc2[r][2], acc2[r][3] };
            *(float4*)(Mb + (size_t)(ty * 4 + r) * C_IN + nj + tx * 4) = v;
        }
    }
}

// ---------------- W[b][o][c] = sum_c5 wo[o][c5] * M[b][c5][c], output bf16 ----------------
__global__ __launch_bounds__(256) void w_kernel(const float* __restrict__ wo,
                                                const float* __restrict__ M,
                                                unsigned short* __restrict__ Wbf) {
    int b = blockIdx.x;
    int o0 = blockIdx.y * 16;
    const float* Mb = M + b * 512 * C_IN;
    unsigned short* Wb = Wbf + b * C_IN * C_IN;
    int tid = threadIdx.x;
    for (int idx = tid; idx < 16 * C_IN; idx += 256) {
        int ol = idx / C_IN, c = idx - ol * C_IN;
        const float* wor = wo + (o0 + ol) * 512;
        float s0 = 0, s1 = 0, s2 = 0, s3 = 0;
        for (int c5 = 0; c5 < 512; c5 += 4) {
            s0 += wor[c5 + 0] * Mb[(c5 + 0) * C_IN + c];
            s1 += wor[c5 + 1] * Mb[(c5 + 1) * C_IN + c];
            s2 += wor[c5 + 2] * Mb[(c5 + 2) * C_IN + c];
            s3 += wor[c5 + 3] * Mb[(c5 + 3) * C_IN + c];
        }
        Wb[(o0 + ol) * C_IN + c] = f2bf((s0 + s1) + (s2 + s3));
    }
}

// ---------------- out = W*x + bo, bf16 MFMA. grid (256, NB), block 256 (4 waves) ----------------
// Block: full M=192, n-slice 128. Wave tile 96m x 64n (6x4 16x16 MFMA tiles).
// ~3 blocks/CU so cross-block MFMA hides each block's staging barrier (R4: 1 blk/CU was latency-bound).
__global__ __launch_bounds__(256) void final_kernel(const float* __restrict__ x,
                                                    const unsigned short* __restrict__ Wbf,
                                                    const float* __restrict__ bo,
                                                    float* __restrict__ out) {
    int n0 = blockIdx.x * 128;
    int b  = blockIdx.y;

    __shared__ unsigned short Xs[128 * 40];

    int tid  = threadIdx.x;
    int wave = tid >> 6;
    int lane = tid & 63;
    int wm   = (wave & 1) * 96;
    int wn   = (wave >> 1) * 64;
    int lm   = lane & 15, quad = lane >> 4;

    int sn  = tid & 127;             // staging n (0..127)
    int skh = (tid >> 7) * 16;       // staging k-half: 0 or 16

    const float* xsrc = x + (size_t)b * C_IN * S_TOT + n0 + sn;
    const unsigned short* Wb = Wbf + b * C_IN * C_IN;

    f32x4 acc[6][4];
#pragma unroll
    for (int mt = 0; mt < 6; mt++)
#pragma unroll
        for (int nt = 0; nt < 4; nt++) acc[mt][nt] = (f32x4){0.f, 0.f, 0.f, 0.f};

    float pf[16];
#pragma unroll
    for (int j = 0; j < 16; j++) pf[j] = xsrc[(size_t)(skh + j) * S_TOT];

    for (int kc = 0; kc < 6; ++kc) {
        int k0 = kc * 32;
        __syncthreads();
        {
            short8 v0, v1;
#pragma unroll
            for (int j = 0; j < 8; j++) { v0[j] = (short)f2bf(pf[j]); v1[j] = (short)f2bf(pf[8 + j]); }
            *(short8*)&Xs[sn * 40 + skh + 0] = v0;
            *(short8*)&Xs[sn * 40 + skh + 8] = v1;
        }
        __syncthreads();
        if (kc + 1 < 6) {
            int kn = k0 + 32;
#pragma unroll
            for (int j = 0; j < 16; j++) pf[j] = xsrc[(size_t)(kn + skh + j) * S_TOT];
        }

        short8 afr[6];
#pragma unroll
        for (int mt = 0; mt < 6; mt++)
            afr[mt] = *(const short8*)(Wb + (size_t)(wm + mt * 16 + lm) * C_IN + k0 + quad * 8);
#pragma unroll
        for (int nt = 0; nt < 4; nt++) {
            short8 bfr = *(const short8*)&Xs[(wn + nt * 16 + lm) * 40 + quad * 8];
#pragma unroll
            for (int mt = 0; mt < 6; mt++)
                acc[mt][nt] = __builtin_amdgcn_mfma_f32_16x16x32_bf16(afr[mt], bfr, acc[mt][nt], 0, 0, 0);
        }
    }

#pragma unroll
    for (int mt = 0; mt < 6; mt++) {
#pragma unroll
        for (int r = 0; r < 4; r++) {
            int m = wm + mt * 16 + quad * 4 + r;
            float bias = bo[m];
            float* op = out + ((size_t)b * C_IN + m) * S_TOT + n0;
#pragma unroll
            for (int nt = 0; nt < 4; nt++)
                op[wn + nt * 16 + lm] = acc[mt][nt][r] + bias;
        }
    }
}

extern "C" void kernel_launch(void* const* d_in, const int* in_sizes, int n_in,
                              void* d_out, int out_size, void* d_ws, size_t ws_size,
                              hipStream_t stream) {
    const float* x  = (const float*)d_in[0];
    const float* wq = (const float*)d_in[1];
    const float* wk = (const float*)d_in[2];
    const float* wv = (const float*)d_in[3];
    const float* wo = (const float*)d_in[4];
    const float* bo = (const float*)d_in[5];
    float* out = (float*)d_out;
    float* ws  = (float*)d_ws;

    float* gG = ws + G_OFF;
    float* gT = ws + T_OFF;
    float* gM = ws + M_OFF;
    unsigned short* gWbf = (unsigned short*)(ws + WBF_OFF);
    float* gP = ws + P_OFF;

    hipMemsetAsync(gG, 0, G_SZ * sizeof(float), stream);

    bool bigws = ws_size >= (size_t)(P_OFF + P_SZ) * sizeof(float);
    if (bigws) {
        gram_partial<<<dim3(NSLICE, NB), 512, 0, stream>>>(x, gP);
        gram_reduce<<<dim3(36, 4, NB), 256, 0, stream>>>(gP, gG);
    } else {
        gram_atomic<<<dim3(NSLICE, NB), 512, 0, stream>>>(x, gG);
    }

    // T[b] = wq (512x192) * G_b (192x192)
    gemm64_kernel<<<dim3(8, 3, NB), 256, 0, stream>>>(
        wq, gG, gT, C_IN, C_IN, 0L, (long)(C_IN * C_IN), (long)(512 * C_IN));

    simsoftm_kernel<<<dim3(NB, NH), 256, 0, stream>>>(gT, wk, wv, gM);

    // W[b] = wo (192x512) * M_b (512x192), bf16 out
    w_kernel<<<dim3(NB, 12), 256, 0, stream>>>(wo, gM, gWbf);

    final_kernel<<<dim3(256, NB), 256, 0, stream>>>(x, gWbf, bo, out);
}

// Round 6
// 263.089 us; speedup vs baseline: 3.1447x; 1.4743x over previous
//
#include <hip/hip_runtime.h>
#include <hip/hip_bf16.h>

#define S_TOT 32768
#define C_IN 192
#define NB 2
#define NH 8
#define DH 64
#define ATT_SCALE 0.125f

// workspace layout (float offsets)
#define G_OFF   0
#define G_SZ    (NB * C_IN * C_IN)        // 73728
#define T_OFF   (G_OFF + G_SZ)
#define T_SZ    (NB * 512 * C_IN)         // 196608
#define M_OFF   (T_OFF + T_SZ)
#define M_SZ    (NB * 512 * C_IN)         // 196608
#define WBF_OFF (M_OFF + M_SZ)
#define WBF_SZ  (NB * C_IN * C_IN / 2)    // bf16 W
#define P_OFF   (WBF_OFF + WBF_SZ)
#define NSLICE  128
#define P_SZ    (NB * NSLICE * C_IN * C_IN)   // 37.75 MB

typedef __attribute__((ext_vector_type(8))) short short8;
typedef __attribute__((ext_vector_type(4))) float f32x4;

__device__ inline unsigned short f2bf(float f) {   // RNE scalar fallback
    unsigned int u = __float_as_uint(f);
    u += 0x7fffu + ((u >> 16) & 1u);
    return (unsigned short)(u >> 16);
}

__device__ inline unsigned int pk_bf16(float a, float b) {  // packed RNE pair
    __hip_bfloat162 t = __float22bfloat162_rn(make_float2(a, b));
    unsigned int bits;
    __builtin_memcpy(&bits, &t, 4);
    return bits;
}

// ---------------- Gram main: P[b][slice] = X-slice * X-slice^T (no atomics) ----------------
#define GR_CH 8
#define GR_BK 32
__global__ __launch_bounds__(512, 2) void gram_partial(const float* __restrict__ x,
                                                       float* __restrict__ P) {
    int b     = blockIdx.y;
    int slice = blockIdx.x;
    int kbase = slice * (GR_CH * GR_BK);

    __shared__ float Ls[GR_BK][196];

    int tid = threadIdx.x;
    int tx  = tid & 15;       // cols tx*12 + cc
    int tyy = tid >> 4;       // rows tyy + 32*rr

    const float* xb = x + (size_t)b * C_IN * S_TOT;

    int lc[3], lkq[3];
#pragma unroll
    for (int q = 0; q < 3; q++) { int id = tid + 512 * q; lc[q] = id >> 3; lkq[q] = id & 7; }

    float acc[6][12] = {};
    float4 pf[3];

#pragma unroll
    for (int q = 0; q < 3; q++)
        pf[q] = *(const float4*)(xb + (size_t)lc[q] * S_TOT + kbase + lkq[q] * 4);

    for (int ch = 0; ch < GR_CH; ++ch) {
        __syncthreads();
#pragma unroll
        for (int q = 0; q < 3; q++) {
            Ls[lkq[q] * 4 + 0][lc[q]] = pf[q].x;
            Ls[lkq[q] * 4 + 1][lc[q]] = pf[q].y;
            Ls[lkq[q] * 4 + 2][lc[q]] = pf[q].z;
            Ls[lkq[q] * 4 + 3][lc[q]] = pf[q].w;
        }
        __syncthreads();
        if (ch + 1 < GR_CH) {
            int k0 = kbase + (ch + 1) * GR_BK;
#pragma unroll
            for (int q = 0; q < 3; q++)
                pf[q] = *(const float4*)(xb + (size_t)lc[q] * S_TOT + k0 + lkq[q] * 4);
        }
#pragma unroll
        for (int kk = 0; kk < GR_BK; ++kk) {
            float a[6];
#pragma unroll
            for (int rr = 0; rr < 6; ++rr) a[rr] = Ls[kk][tyy + 32 * rr];
            float4 c0 = *(const float4*)&Ls[kk][tx * 12];
            float4 c1 = *(const float4*)&Ls[kk][tx * 12 + 4];
            float4 c2 = *(const float4*)&Ls[kk][tx * 12 + 8];
            float bb[12] = { c0.x, c0.y, c0.z, c0.w, c1.x, c1.y, c1.z, c1.w, c2.x, c2.y, c2.z, c2.w };
#pragma unroll
            for (int rr = 0; rr < 6; ++rr)
#pragma unroll
                for (int cc = 0; cc < 12; ++cc)
                    acc[rr][cc] = fmaf(a[rr], bb[cc], acc[rr][cc]);
        }
    }

    float* Pb = P + ((size_t)(b * NSLICE + slice)) * (C_IN * C_IN);
#pragma unroll
    for (int rr = 0; rr < 6; ++rr) {
        float* row = Pb + (tyy + 32 * rr) * C_IN + tx * 12;
#pragma unroll
        for (int u = 0; u < 3; u++) {
            float4 v = { acc[rr][u * 4 + 0], acc[rr][u * 4 + 1], acc[rr][u * 4 + 2], acc[rr][u * 4 + 3] };
            *(float4*)(row + u * 4) = v;
        }
    }
}

// ---------------- Gram reduce ----------------
__global__ __launch_bounds__(256) void gram_reduce(const float* __restrict__ P,
                                                   float* __restrict__ G) {
    int b  = blockIdx.z;
    int s0 = blockIdx.y * (NSLICE / 4);
    int idx4 = (blockIdx.x * 256 + threadIdx.x) * 4;

    const float* Pb = P + ((size_t)(b * NSLICE + s0)) * (C_IN * C_IN) + idx4;
    float4 acc = {0.f, 0.f, 0.f, 0.f};
#pragma unroll 4
    for (int s = 0; s < NSLICE / 4; ++s) {
        float4 v = *(const float4*)(Pb + (size_t)s * (C_IN * C_IN));
        acc.x += v.x; acc.y += v.y; acc.z += v.z; acc.w += v.w;
    }
    float* g = G + (size_t)b * C_IN * C_IN + idx4;
    atomicAdd(g + 0, acc.x);
    atomicAdd(g + 1, acc.y);
    atomicAdd(g + 2, acc.z);
    atomicAdd(g + 3, acc.w);
}

// ---------------- Gram fallback (atomic, coalesced cols) ----------------
__global__ __launch_bounds__(512, 2) void gram_atomic(const float* __restrict__ x,
                                                      float* __restrict__ G) {
    int b     = blockIdx.y;
    int kbase = blockIdx.x * (GR_CH * GR_BK);

    __shared__ float Ls[GR_BK][196];

    int tid = threadIdx.x;
    int tx  = tid & 15;
    int tyy = tid >> 4;

    const float* xb = x + (size_t)b * C_IN * S_TOT;

    int lc[3], lkq[3];
#pragma unroll
    for (int q = 0; q < 3; q++) { int id = tid + 512 * q; lc[q] = id >> 3; lkq[q] = id & 7; }

    float acc[6][12] = {};
    float4 pf[3];

#pragma unroll
    for (int q = 0; q < 3; q++)
        pf[q] = *(const float4*)(xb + (size_t)lc[q] * S_TOT + kbase + lkq[q] * 4);

    for (int ch = 0; ch < GR_CH; ++ch) {
        __syncthreads();
#pragma unroll
        for (int q = 0; q < 3; q++) {
            Ls[lkq[q] * 4 + 0][lc[q]] = pf[q].x;
            Ls[lkq[q] * 4 + 1][lc[q]] = pf[q].y;
            Ls[lkq[q] * 4 + 2][lc[q]] = pf[q].z;
            Ls[lkq[q] * 4 + 3][lc[q]] = pf[q].w;
        }
        __syncthreads();
        if (ch + 1 < GR_CH) {
            int k0 = kbase + (ch + 1) * GR_BK;
#pragma unroll
            for (int q = 0; q < 3; q++)
                pf[q] = *(const float4*)(xb + (size_t)lc[q] * S_TOT + k0 + lkq[q] * 4);
        }
#pragma unroll
        for (int kk = 0; kk < GR_BK; ++kk) {
            float a[6], bb[12];
#pragma unroll
            for (int rr = 0; rr < 6; ++rr)  a[rr] = Ls[kk][tyy + 32 * rr];
#pragma unroll
            for (int cc = 0; cc < 12; ++cc) bb[cc] = Ls[kk][tx + 16 * cc];
#pragma unroll
            for (int rr = 0; rr < 6; ++rr)
#pragma unroll
                for (int cc = 0; cc < 12; ++cc)
                    acc[rr][cc] = fmaf(a[rr], bb[cc], acc[rr][cc]);
        }
    }

    float* Gb = G + b * C_IN * C_IN;
#pragma unroll
    for (int rr = 0; rr < 6; ++rr)
#pragma unroll
        for (int cc = 0; cc < 12; ++cc)
            atomicAdd(&Gb[(tyy + 32 * rr) * C_IN + tx + 16 * cc], acc[rr][cc]);
}

// ---------------- generic 64x64-tile GEMM (fp32 out) ----------------
__global__ __launch_bounds__(256) void gemm64_kernel(const float* __restrict__ A,
                                                     const float* __restrict__ B,
                                                     float* __restrict__ C,
                                                     int K, int N,
                                                     long aStride, long bStride, long cStride) {
    int mi0 = blockIdx.x * 64;
    int nj0 = blockIdx.y * 64;
    int b   = blockIdx.z;

    __shared__ float As[16][68];
    __shared__ float Bs[16][68];

    int tid = threadIdx.x;
    int tx = tid & 15, ty = tid >> 4;
    int lrow = tid >> 2, lk = (tid & 3) * 4;
    int ldk = tid >> 4, ldn = (tid & 15) * 4;

    const float* Ab = A + b * aStride;
    const float* Bb = B + b * bStride;

    float acc[4][4] = {};

    for (int k0 = 0; k0 < K; k0 += 16) {
        float4 av = *(const float4*)(Ab + (size_t)(mi0 + lrow) * K + k0 + lk);
        float4 bv = *(const float4*)(Bb + (size_t)(k0 + ldk) * N + nj0 + ldn);
        __syncthreads();
        As[lk + 0][lrow] = av.x; As[lk + 1][lrow] = av.y;
        As[lk + 2][lrow] = av.z; As[lk + 3][lrow] = av.w;
        *(float4*)&Bs[ldk][ldn] = bv;
        __syncthreads();
#pragma unroll
        for (int kk = 0; kk < 16; kk++) {
            float4 a = *(const float4*)&As[kk][ty * 4];
            float4 bb = *(const float4*)&Bs[kk][tx * 4];
            acc[0][0] += a.x * bb.x; acc[0][1] += a.x * bb.y; acc[0][2] += a.x * bb.z; acc[0][3] += a.x * bb.w;
            acc[1][0] += a.y * bb.x; acc[1][1] += a.y * bb.y; acc[1][2] += a.y * bb.z; acc[1][3] += a.y * bb.w;
            acc[2][0] += a.z * bb.x; acc[2][1] += a.z * bb.y; acc[2][2] += a.z * bb.z; acc[2][3] += a.z * bb.w;
            acc[3][0] += a.w * bb.x; acc[3][1] += a.w * bb.y; acc[3][2] += a.w * bb.z; acc[3][3] += a.w * bb.w;
        }
    }

    float* Cb = C + b * cStride;
#pragma unroll
    for (int r = 0; r < 4; r++) {
        float4 v = { acc[r][0], acc[r][1], acc[r][2], acc[r][3] };
        *(float4*)(Cb + (size_t)(mi0 + ty * 4 + r) * N + nj0 + tx * 4) = v;
    }
}

// ---------------- same GEMM, bf16 packed output (for W) ----------------
__global__ __launch_bounds__(256) void gemm64bf_kernel(const float* __restrict__ A,
                                                       const float* __restrict__ B,
                                                       unsigned short* __restrict__ C,
                                                       int K, int N,
                                                       long aStride, long bStride, long cStride) {
    int mi0 = blockIdx.x * 64;
    int nj0 = blockIdx.y * 64;
    int b   = blockIdx.z;

    __shared__ float As[16][68];
    __shared__ float Bs[16][68];

    int tid = threadIdx.x;
    int tx = tid & 15, ty = tid >> 4;
    int lrow = tid >> 2, lk = (tid & 3) * 4;
    int ldk = tid >> 4, ldn = (tid & 15) * 4;

    const float* Ab = A + b * aStride;
    const float* Bb = B + b * bStride;

    float acc[4][4] = {};

    for (int k0 = 0; k0 < K; k0 += 16) {
        float4 av = *(const float4*)(Ab + (size_t)(mi0 + lrow) * K + k0 + lk);
        float4 bv = *(const float4*)(Bb + (size_t)(k0 + ldk) * N + nj0 + ldn);
        __syncthreads();
        As[lk + 0][lrow] = av.x; As[lk + 1][lrow] = av.y;
        As[lk + 2][lrow] = av.z; As[lk + 3][lrow] = av.w;
        *(float4*)&Bs[ldk][ldn] = bv;
        __syncthreads();
#pragma unroll
        for (int kk = 0; kk < 16; kk++) {
            float4 a = *(const float4*)&As[kk][ty * 4];
            float4 bb = *(const float4*)&Bs[kk][tx * 4];
            acc[0][0] += a.x * bb.x; acc[0][1] += a.x * bb.y; acc[0][2] += a.x * bb.z; acc[0][3] += a.x * bb.w;
            acc[1][0] += a.y * bb.x; acc[1][1] += a.y * bb.y; acc[1][2] += a.y * bb.z; acc[1][3] += a.y * bb.w;
            acc[2][0] += a.z * bb.x; acc[2][1] += a.z * bb.y; acc[2][2] += a.z * bb.z; acc[2][3] += a.z * bb.w;
            acc[3][0] += a.w * bb.x; acc[3][1] += a.w * bb.y; acc[3][2] += a.w * bb.z; acc[3][3] += a.w * bb.w;
        }
    }

    unsigned short* Cb = C + b * cStride;
#pragma unroll
    for (int r = 0; r < 4; r++) {
        union { unsigned long long q; unsigned int u[2]; } pk;
        pk.u[0] = pk_bf16(acc[r][0], acc[r][1]);
        pk.u[1] = pk_bf16(acc[r][2], acc[r][3]);
        *(unsigned long long*)&Cb[(size_t)(mi0 + ty * 4 + r) * N + nj0 + tx * 4] = pk.q;
    }
}

// ---------------- fused: sim = T_h wk_h^T * SCALE -> softmax -> M_h = attn * wv_h (fp32) ----------------
__global__ __launch_bounds__(256) void simsoftm_kernel(const float* __restrict__ T,
                                                       const float* __restrict__ wk,
                                                       const float* __restrict__ wv,
                                                       float* __restrict__ M) {
    int b = blockIdx.x, h = blockIdx.y;

    __shared__ float As[16][68];
    __shared__ float Bs[16][68];
    __shared__ float At[64][68];

    int tid = threadIdx.x;
    int tx = tid & 15, ty = tid >> 4;
    int lrow = tid >> 2, lk = (tid & 3) * 4;
    int ldk = tid >> 4, ldn = (tid & 15) * 4;

    const float* Th  = T + (size_t)b * 512 * C_IN + (size_t)(h * 64) * C_IN;
    const float* wkh = wk + (size_t)(h * 64) * C_IN;
    const float* wvh = wv + (size_t)(h * 64) * C_IN;

    float acc[4][4] = {};
    for (int k0 = 0; k0 < C_IN; k0 += 16) {
        float4 av = *(const float4*)(Th  + (size_t)lrow * C_IN + k0 + lk);
        float4 bv = *(const float4*)(wkh + (size_t)lrow * C_IN + k0 + lk);
        __syncthreads();
        As[lk + 0][lrow] = av.x; As[lk + 1][lrow] = av.y;
        As[lk + 2][lrow] = av.z; As[lk + 3][lrow] = av.w;
        Bs[lk + 0][lrow] = bv.x; Bs[lk + 1][lrow] = bv.y;
        Bs[lk + 2][lrow] = bv.z; Bs[lk + 3][lrow] = bv.w;
        __syncthreads();
#pragma unroll
        for (int kk = 0; kk < 16; kk++) {
            float4 a = *(const float4*)&As[kk][ty * 4];
            float4 bb = *(const float4*)&Bs[kk][tx * 4];
            acc[0][0] += a.x * bb.x; acc[0][1] += a.x * bb.y; acc[0][2] += a.x * bb.z; acc[0][3] += a.x * bb.w;
            acc[1][0] += a.y * bb.x; acc[1][1] += a.y * bb.y; acc[1][2] += a.y * bb.z; acc[1][3] += a.y * bb.w;
            acc[2][0] += a.z * bb.x; acc[2][1] += a.z * bb.y; acc[2][2] += a.z * bb.z; acc[2][3] += a.z * bb.w;
            acc[3][0] += a.w * bb.x; acc[3][1] += a.w * bb.y; acc[3][2] += a.w * bb.z; acc[3][3] += a.w * bb.w;
        }
    }

#pragma unroll
    for (int r = 0; r < 4; r++) {
        float s0 = acc[r][0] * ATT_SCALE, s1 = acc[r][1] * ATT_SCALE;
        float s2 = acc[r][2] * ATT_SCALE, s3 = acc[r][3] * ATT_SCALE;
        float mx = fmaxf(fmaxf(s0, s1), fmaxf(s2, s3));
        mx = fmaxf(mx, __shfl_xor(mx, 1));
        mx = fmaxf(mx, __shfl_xor(mx, 2));
        mx = fmaxf(mx, __shfl_xor(mx, 4));
        mx = fmaxf(mx, __shfl_xor(mx, 8));
        float e0 = __expf(s0 - mx), e1 = __expf(s1 - mx);
        float e2 = __expf(s2 - mx), e3 = __expf(s3 - mx);
        float sum = (e0 + e1) + (e2 + e3);
        sum += __shfl_xor(sum, 1);
        sum += __shfl_xor(sum, 2);
        sum += __shfl_xor(sum, 4);
        sum += __shfl_xor(sum, 8);
        float inv = 1.0f / sum;
        At[tx * 4 + 0][ty * 4 + r] = e0 * inv;
        At[tx * 4 + 1][ty * 4 + r] = e1 * inv;
        At[tx * 4 + 2][ty * 4 + r] = e2 * inv;
        At[tx * 4 + 3][ty * 4 + r] = e3 * inv;
    }

    float* Mb = M + (size_t)b * 512 * C_IN + (size_t)(h * 64) * C_IN;
    for (int nj = 0; nj < C_IN; nj += 64) {
        float acc2[4][4] = {};
        for (int j0 = 0; j0 < 64; j0 += 16) {
            float4 bv = *(const float4*)(wvh + (size_t)(j0 + ldk) * C_IN + nj + ldn);
            __syncthreads();
            *(float4*)&Bs[ldk][ldn] = bv;
            __syncthreads();
#pragma unroll
            for (int kk = 0; kk < 16; kk++) {
                float4 a = *(const float4*)&At[j0 + kk][ty * 4];
                float4 bb = *(const float4*)&Bs[kk][tx * 4];
                acc2[0][0] += a.x * bb.x; acc2[0][1] += a.x * bb.y; acc2[0][2] += a.x * bb.z; acc2[0][3] += a.x * bb.w;
                acc2[1][0] += a.y * bb.x; acc2[1][1] += a.y * bb.y; acc2[1][2] += a.y * bb.z; acc2[1][3] += a.y * bb.w;
                acc2[2][0] += a.z * bb.x; acc2[2][1] += a.z * bb.y; acc2[2][2] += a.z * bb.z; acc2[2][3] += a.z * bb.w;
                acc2[3][0] += a.w * bb.x; acc2[3][1] += a.w * bb.y; acc2[3][2] += a.w * bb.z; acc2[3][3] += a.w * bb.w;
            }
        }
#pragma unroll
        for (int r = 0; r < 4; r++) {
            float4 v = { acc2[r][0], acc2[r][1], acc2[r][2], acc2[r][3] };
            *(float4*)(Mb + (size_t)(ty * 4 + r) * C_IN + nj + tx * 4) = v;
        }
    }
}

// ---------------- out = W*x + bo, bf16 MFMA. grid (256, NB), block 256 (4 waves) ----------------
__global__ __launch_bounds__(256) void final_kernel(const float* __restrict__ x,
                                                    const unsigned short* __restrict__ Wbf,
                                                    const float* __restrict__ bo,
                                                    float* __restrict__ out) {
    int n0 = blockIdx.x * 128;
    int b  = blockIdx.y;

    __shared__ unsigned short Xs[128 * 40];

    int tid  = threadIdx.x;
    int wave = tid >> 6;
    int lane = tid & 63;
    int wm   = (wave & 1) * 96;
    int wn   = (wave >> 1) * 64;
    int lm   = lane & 15, quad = lane >> 4;

    int sn  = tid & 127;
    int skh = (tid >> 7) * 16;

    const float* xsrc = x + (size_t)b * C_IN * S_TOT + n0 + sn;
    const unsigned short* Wb = Wbf + b * C_IN * C_IN;

    f32x4 acc[6][4];
#pragma unroll
    for (int mt = 0; mt < 6; mt++)
#pragma unroll
        for (int nt = 0; nt < 4; nt++) acc[mt][nt] = (f32x4){0.f, 0.f, 0.f, 0.f};

    float pf[16];
#pragma unroll
    for (int j = 0; j < 16; j++) pf[j] = xsrc[(size_t)(skh + j) * S_TOT];

    for (int kc = 0; kc < 6; ++kc) {
        int k0 = kc * 32;
        __syncthreads();
        {
            union { uint4 q; unsigned int u[4]; } pk0, pk1;
#pragma unroll
            for (int j = 0; j < 4; j++) {
                pk0.u[j] = pk_bf16(pf[2 * j],     pf[2 * j + 1]);
                pk1.u[j] = pk_bf16(pf[8 + 2 * j], pf[8 + 2 * j + 1]);
            }
            *(uint4*)&Xs[sn * 40 + skh + 0] = pk0.q;
            *(uint4*)&Xs[sn * 40 + skh + 8] = pk1.q;
        }
        __syncthreads();
        if (kc + 1 < 6) {
            int kn = k0 + 32;
#pragma unroll
            for (int j = 0; j < 16; j++) pf[j] = xsrc[(size_t)(kn + skh + j) * S_TOT];
        }

        short8 afr[6];
#pragma unroll
        for (int mt = 0; mt < 6; mt++)
            afr[mt] = *(const short8*)(Wb + (size_t)(wm + mt * 16 + lm) * C_IN + k0 + quad * 8);
#pragma unroll
        for (int nt = 0; nt < 4; nt++) {
            short8 bfr = *(const short8*)&Xs[(wn + nt * 16 + lm) * 40 + quad * 8];
#pragma unroll
            for (int mt = 0; mt < 6; mt++)
                acc[mt][nt] = __builtin_amdgcn_mfma_f32_16x16x32_bf16(afr[mt], bfr, acc[mt][nt], 0, 0, 0);
        }
    }

#pragma unroll
    for (int mt = 0; mt < 6; mt++) {
#pragma unroll
        for (int r = 0; r < 4; r++) {
            int m = wm + mt * 16 + quad * 4 + r;
            float bias = bo[m];
            float* op = out + ((size_t)b * C_IN + m) * S_TOT + n0;
#pragma unroll
            for (int nt = 0; nt < 4; nt++)
                op[wn + nt * 16 + lm] = acc[mt][nt][r] + bias;
        }
    }
}

extern "C" void kernel_launch(void* const* d_in, const int* in_sizes, int n_in,
                              void* d_out, int out_size, void* d_ws, size_t ws_size,
                              hipStream_t stream) {
    const float* x  = (const float*)d_in[0];
    const float* wq = (const float*)d_in[1];
    const float* wk = (const float*)d_in[2];
    const float* wv = (const float*)d_in[3];
    const float* wo = (const float*)d_in[4];
    const float* bo = (const float*)d_in[5];
    float* out = (float*)d_out;
    float* ws  = (float*)d_ws;

    float* gG = ws + G_OFF;
    float* gT = ws + T_OFF;
    float* gM = ws + M_OFF;
    unsigned short* gWbf = (unsigned short*)(ws + WBF_OFF);
    float* gP = ws + P_OFF;

    hipMemsetAsync(gG, 0, G_SZ * sizeof(float), stream);

    bool bigws = ws_size >= (size_t)(P_OFF + P_SZ) * sizeof(float);
    if (bigws) {
        gram_partial<<<dim3(NSLICE, NB), 512, 0, stream>>>(x, gP);
        gram_reduce<<<dim3(36, 4, NB), 256, 0, stream>>>(gP, gG);
    } else {
        gram_atomic<<<dim3(NSLICE, NB), 512, 0, stream>>>(x, gG);
    }

    // T[b] = wq (512x192) * G_b (192x192)
    gemm64_kernel<<<dim3(8, 3, NB), 256, 0, stream>>>(
        wq, gG, gT, C_IN, C_IN, 0L, (long)(C_IN * C_IN), (long)(512 * C_IN));

    simsoftm_kernel<<<dim3(NB, NH), 256, 0, stream>>>(gT, wk, wv, gM);

    // W[b] = wo (192x512) * M_b (512x192), bf16 packed out
    gemm64bf_kernel<<<dim3(3, 3, NB), 256, 0, stream>>>(
        wo, gM, gWbf, 512, C_IN, 0L, (long)(512 * C_IN), (long)(C_IN * C_IN));

    final_kernel<<<dim3(256, NB), 256, 0, stream>>>(x, gWbf, bo, out);
}

// Round 7
// 219.329 us; speedup vs baseline: 3.7721x; 1.1995x over previous
//
#include <hip/hip_runtime.h>
#include <hip/hip_bf16.h>

#define S_TOT 32768
#define C_IN 192
#define NB 2
#define NH 8
#define DH 64
#define ATT_SCALE 0.125f

// workspace layout (float offsets)
#define G_OFF   0
#define G_SZ    (NB * C_IN * C_IN)        // 73728
#define T_OFF   (G_OFF + G_SZ)
#define T_SZ    (NB * 512 * C_IN)         // 196608
#define M_OFF   (T_OFF + T_SZ)
#define M_SZ    (NB * 512 * C_IN)         // 196608
#define WBF_OFF (M_OFF + M_SZ)
#define WBF_SZ  (NB * C_IN * C_IN / 2)    // bf16 W
#define P_OFF   (WBF_OFF + WBF_SZ)
#define NSLICE  128
#define P_SZ    (NB * NSLICE * C_IN * C_IN)   // 37.75 MB

typedef __attribute__((ext_vector_type(8))) short short8;
typedef __attribute__((ext_vector_type(4))) float f32x4;

__device__ inline unsigned short f2bf(float f) {   // RNE
    unsigned int u = __float_as_uint(f);
    u += 0x7fffu + ((u >> 16) & 1u);
    return (unsigned short)(u >> 16);
}

__device__ inline unsigned int pk_bf16(float a, float b) {  // packed RNE pair
    __hip_bfloat162 t = __float22bfloat162_rn(make_float2(a, b));
    unsigned int bits;
    __builtin_memcpy(&bits, &t, 4);
    return bits;
}

// split x = hi + lo: hi = truncated bf16 (1 op), lo = RNE bf16 of exact remainder.
// x - (hi+lo) ~ 2^-17 |x|  ->  G error ~1e-5 relative after dropping lo*lo.
__device__ inline void split_bf(float v, unsigned short& h, unsigned short& l) {
    unsigned int u = __float_as_uint(v);
    h = (unsigned short)(u >> 16);
    float hf = __uint_as_float(u & 0xffff0000u);
    l = f2bf(v - hf);
}

// ---------------- Gram via split-bf16 MFMA: P[b][slice] = X-slice * X-slice^T ----------------
// grid (128, NB), block 512 (8 waves). k-slice 256 = 8 chunks of 32.
// LDS: Hs/Lo [192][40] ushort (stride 40 = conflict-free, final_kernel-proven).
// Wave (rw=wave&3, cw=wave>>2): 3 row-tiles x 6 col-tiles of 16x16; 3 MFMA each (hh, hl, lh).
#define GR_CH 8
#define GR_BK 32
__global__ __launch_bounds__(512, 2) void gram_partial(const float* __restrict__ x,
                                                       float* __restrict__ P) {
    int b     = blockIdx.y;
    int slice = blockIdx.x;
    int kbase = slice * (GR_CH * GR_BK);

    __shared__ unsigned short Hs[192 * 40];
    __shared__ unsigned short Lo[192 * 40];

    int tid  = threadIdx.x;
    int wave = tid >> 6;
    int lane = tid & 63;
    int rw   = wave & 3;          // row-tile group: rows 48*rw .. +47
    int cw   = wave >> 2;         // col-tile group: cols 96*cw .. +95
    int lm   = lane & 15, quad = lane >> 4;

    const float* xb = x + (size_t)b * C_IN * S_TOT;

    // loader: 3 float4/thread/chunk; id -> row lc = id>>3 (0..191), k-quad lkq = id&7
    int lc[3], lkq[3];
#pragma unroll
    for (int q = 0; q < 3; q++) { int id = tid + 512 * q; lc[q] = id >> 3; lkq[q] = id & 7; }

    f32x4 acc[3][6];
#pragma unroll
    for (int mt = 0; mt < 3; mt++)
#pragma unroll
        for (int nt = 0; nt < 6; nt++) acc[mt][nt] = (f32x4){0.f, 0.f, 0.f, 0.f};

    float4 pf[3];
#pragma unroll
    for (int q = 0; q < 3; q++)
        pf[q] = *(const float4*)(xb + (size_t)lc[q] * S_TOT + kbase + lkq[q] * 4);

    for (int ch = 0; ch < GR_CH; ++ch) {
        __syncthreads();
#pragma unroll
        for (int q = 0; q < 3; q++) {
            unsigned short h[4], l[4];
            split_bf(pf[q].x, h[0], l[0]);
            split_bf(pf[q].y, h[1], l[1]);
            split_bf(pf[q].z, h[2], l[2]);
            split_bf(pf[q].w, h[3], l[3]);
            unsigned long long hq = (unsigned long long)h[0] | ((unsigned long long)h[1] << 16)
                                  | ((unsigned long long)h[2] << 32) | ((unsigned long long)h[3] << 48);
            unsigned long long lq = (unsigned long long)l[0] | ((unsigned long long)l[1] << 16)
                                  | ((unsigned long long)l[2] << 32) | ((unsigned long long)l[3] << 48);
            *(unsigned long long*)&Hs[lc[q] * 40 + lkq[q] * 4] = hq;
            *(unsigned long long*)&Lo[lc[q] * 40 + lkq[q] * 4] = lq;
        }
        __syncthreads();
        if (ch + 1 < GR_CH) {
            int k0 = kbase + (ch + 1) * GR_BK;
#pragma unroll
            for (int q = 0; q < 3; q++)
                pf[q] = *(const float4*)(xb + (size_t)lc[q] * S_TOT + k0 + lkq[q] * 4);
        }

        // A frags (rows of this wave's row group), hi+lo, resident all chunk
        short8 ah[3], al[3];
#pragma unroll
        for (int mt = 0; mt < 3; mt++) {
            int row = 48 * rw + mt * 16 + lm;
            ah[mt] = *(const short8*)&Hs[row * 40 + quad * 8];
            al[mt] = *(const short8*)&Lo[row * 40 + quad * 8];
        }
#pragma unroll
        for (int nt = 0; nt < 6; nt++) {
            int col = 96 * cw + nt * 16 + lm;
            short8 bh = *(const short8*)&Hs[col * 40 + quad * 8];
            short8 bl = *(const short8*)&Lo[col * 40 + quad * 8];
#pragma unroll
            for (int mt = 0; mt < 3; mt++) {
                acc[mt][nt] = __builtin_amdgcn_mfma_f32_16x16x32_bf16(ah[mt], bh, acc[mt][nt], 0, 0, 0);
                acc[mt][nt] = __builtin_amdgcn_mfma_f32_16x16x32_bf16(ah[mt], bl, acc[mt][nt], 0, 0, 0);
                acc[mt][nt] = __builtin_amdgcn_mfma_f32_16x16x32_bf16(al[mt], bh, acc[mt][nt], 0, 0, 0);
            }
        }
    }

    float* Pb = P + ((size_t)(b * NSLICE + slice)) * (C_IN * C_IN);
#pragma unroll
    for (int mt = 0; mt < 3; mt++) {
#pragma unroll
        for (int r = 0; r < 4; r++) {
            int row = 48 * rw + mt * 16 + quad * 4 + r;
#pragma unroll
            for (int nt = 0; nt < 6; nt++)
                Pb[row * C_IN + 96 * cw + nt * 16 + lm] = acc[mt][nt][r];
        }
    }
}

// ---------------- Gram reduce ----------------
__global__ __launch_bounds__(256) void gram_reduce(const float* __restrict__ P,
                                                   float* __restrict__ G) {
    int b  = blockIdx.z;
    int s0 = blockIdx.y * (NSLICE / 4);
    int idx4 = (blockIdx.x * 256 + threadIdx.x) * 4;

    const float* Pb = P + ((size_t)(b * NSLICE + s0)) * (C_IN * C_IN) + idx4;
    float4 acc = {0.f, 0.f, 0.f, 0.f};
#pragma unroll 4
    for (int s = 0; s < NSLICE / 4; ++s) {
        float4 v = *(const float4*)(Pb + (size_t)s * (C_IN * C_IN));
        acc.x += v.x; acc.y += v.y; acc.z += v.z; acc.w += v.w;
    }
    float* g = G + (size_t)b * C_IN * C_IN + idx4;
    atomicAdd(g + 0, acc.x);
    atomicAdd(g + 1, acc.y);
    atomicAdd(g + 2, acc.z);
    atomicAdd(g + 3, acc.w);
}

// ---------------- Gram fallback (fp32 atomic, coalesced cols; used if ws too small) ----------------
__global__ __launch_bounds__(512, 2) void gram_atomic(const float* __restrict__ x,
                                                      float* __restrict__ G) {
    int b     = blockIdx.y;
    int kbase = blockIdx.x * (GR_CH * GR_BK);

    __shared__ float Ls[GR_BK][196];

    int tid = threadIdx.x;
    int tx  = tid & 15;
    int tyy = tid >> 4;

    const float* xb = x + (size_t)b * C_IN * S_TOT;

    int lc[3], lkq[3];
#pragma unroll
    for (int q = 0; q < 3; q++) { int id = tid + 512 * q; lc[q] = id >> 3; lkq[q] = id & 7; }

    float acc[6][12] = {};
    float4 pf[3];

#pragma unroll
    for (int q = 0; q < 3; q++)
        pf[q] = *(const float4*)(xb + (size_t)lc[q] * S_TOT + kbase + lkq[q] * 4);

    for (int ch = 0; ch < GR_CH; ++ch) {
        __syncthreads();
#pragma unroll
        for (int q = 0; q < 3; q++) {
            Ls[lkq[q] * 4 + 0][lc[q]] = pf[q].x;
            Ls[lkq[q] * 4 + 1][lc[q]] = pf[q].y;
            Ls[lkq[q] * 4 + 2][lc[q]] = pf[q].z;
            Ls[lkq[q] * 4 + 3][lc[q]] = pf[q].w;
        }
        __syncthreads();
        if (ch + 1 < GR_CH) {
            int k0 = kbase + (ch + 1) * GR_BK;
#pragma unroll
            for (int q = 0; q < 3; q++)
                pf[q] = *(const float4*)(xb + (size_t)lc[q] * S_TOT + k0 + lkq[q] * 4);
        }
#pragma unroll
        for (int kk = 0; kk < GR_BK; ++kk) {
            float a[6], bb[12];
#pragma unroll
            for (int rr = 0; rr < 6; ++rr)  a[rr] = Ls[kk][tyy + 32 * rr];
#pragma unroll
            for (int cc = 0; cc < 12; ++cc) bb[cc] = Ls[kk][tx + 16 * cc];
#pragma unroll
            for (int rr = 0; rr < 6; ++rr)
#pragma unroll
                for (int cc = 0; cc < 12; ++cc)
                    acc[rr][cc] = fmaf(a[rr], bb[cc], acc[rr][cc]);
        }
    }

    float* Gb = G + b * C_IN * C_IN;
#pragma unroll
    for (int rr = 0; rr < 6; ++rr)
#pragma unroll
        for (int cc = 0; cc < 12; ++cc)
            atomicAdd(&Gb[(tyy + 32 * rr) * C_IN + tx + 16 * cc], acc[rr][cc]);
}

// ---------------- generic 64x64-tile GEMM (fp32 out) ----------------
__global__ __launch_bounds__(256) void gemm64_kernel(const float* __restrict__ A,
                                                     const float* __restrict__ B,
                                                     float* __restrict__ C,
                                                     int K, int N,
                                                     long aStride, long bStride, long cStride) {
    int mi0 = blockIdx.x * 64;
    int nj0 = blockIdx.y * 64;
    int b   = blockIdx.z;

    __shared__ float As[16][68];
    __shared__ float Bs[16][68];

    int tid = threadIdx.x;
    int tx = tid & 15, ty = tid >> 4;
    int lrow = tid >> 2, lk = (tid & 3) * 4;
    int ldk = tid >> 4, ldn = (tid & 15) * 4;

    const float* Ab = A + b * aStride;
    const float* Bb = B + b * bStride;

    float acc[4][4] = {};

    for (int k0 = 0; k0 < K; k0 += 16) {
        float4 av = *(const float4*)(Ab + (size_t)(mi0 + lrow) * K + k0 + lk);
        float4 bv = *(const float4*)(Bb + (size_t)(k0 + ldk) * N + nj0 + ldn);
        __syncthreads();
        As[lk + 0][lrow] = av.x; As[lk + 1][lrow] = av.y;
        As[lk + 2][lrow] = av.z; As[lk + 3][lrow] = av.w;
        *(float4*)&Bs[ldk][ldn] = bv;
        __syncthreads();
#pragma unroll
        for (int kk = 0; kk < 16; kk++) {
            float4 a = *(const float4*)&As[kk][ty * 4];
            float4 bb = *(const float4*)&Bs[kk][tx * 4];
            acc[0][0] += a.x * bb.x; acc[0][1] += a.x * bb.y; acc[0][2] += a.x * bb.z; acc[0][3] += a.x * bb.w;
            acc[1][0] += a.y * bb.x; acc[1][1] += a.y * bb.y; acc[1][2] += a.y * bb.z; acc[1][3] += a.y * bb.w;
            acc[2][0] += a.z * bb.x; acc[2][1] += a.z * bb.y; acc[2][2] += a.z * bb.z; acc[2][3] += a.z * bb.w;
            acc[3][0] += a.w * bb.x; acc[3][1] += a.w * bb.y; acc[3][2] += a.w * bb.z; acc[3][3] += a.w * bb.w;
        }
    }

    float* Cb = C + b * cStride;
#pragma unroll
    for (int r = 0; r < 4; r++) {
        float4 v = { acc[r][0], acc[r][1], acc[r][2], acc[r][3] };
        *(float4*)(Cb + (size_t)(mi0 + ty * 4 + r) * N + nj0 + tx * 4) = v;
    }
}

// ---------------- same GEMM, bf16 packed output (for W) ----------------
__global__ __launch_bounds__(256) void gemm64bf_kernel(const float* __restrict__ A,
                                                       const float* __restrict__ B,
                                                       unsigned short* __restrict__ C,
                                                       int K, int N,
                                                       long aStride, long bStride, long cStride) {
    int mi0 = blockIdx.x * 64;
    int nj0 = blockIdx.y * 64;
    int b   = blockIdx.z;

    __shared__ float As[16][68];
    __shared__ float Bs[16][68];

    int tid = threadIdx.x;
    int tx = tid & 15, ty = tid >> 4;
    int lrow = tid >> 2, lk = (tid & 3) * 4;
    int ldk = tid >> 4, ldn = (tid & 15) * 4;

    const float* Ab = A + b * aStride;
    const float* Bb = B + b * bStride;

    float acc[4][4] = {};

    for (int k0 = 0; k0 < K; k0 += 16) {
        float4 av = *(const float4*)(Ab + (size_t)(mi0 + lrow) * K + k0 + lk);
        float4 bv = *(const float4*)(Bb + (size_t)(k0 + ldk) * N + nj0 + ldn);
        __syncthreads();
        As[lk + 0][lrow] = av.x; As[lk + 1][lrow] = av.y;
        As[lk + 2][lrow] = av.z; As[lk + 3][lrow] = av.w;
        *(float4*)&Bs[ldk][ldn] = bv;
        __syncthreads();
#pragma unroll
        for (int kk = 0; kk < 16; kk++) {
            float4 a = *(const float4*)&As[kk][ty * 4];
            float4 bb = *(const float4*)&Bs[kk][tx * 4];
            acc[0][0] += a.x * bb.x; acc[0][1] += a.x * bb.y; acc[0][2] += a.x * bb.z; acc[0][3] += a.x * bb.w;
            acc[1][0] += a.y * bb.x; acc[1][1] += a.y * bb.y; acc[1][2] += a.y * bb.z; acc[1][3] += a.y * bb.w;
            acc[2][0] += a.z * bb.x; acc[2][1] += a.z * bb.y; acc[2][2] += a.z * bb.z; acc[2][3] += a.z * bb.w;
            acc[3][0] += a.w * bb.x; acc[3][1] += a.w * bb.y; acc[3][2] += a.w * bb.z; acc[3][3] += a.w * bb.w;
        }
    }

    unsigned short* Cb = C + b * cStride;
#pragma unroll
    for (int r = 0; r < 4; r++) {
        union { unsigned long long q; unsigned int u[2]; } pk;
        pk.u[0] = pk_bf16(acc[r][0], acc[r][1]);
        pk.u[1] = pk_bf16(acc[r][2], acc[r][3]);
        *(unsigned long long*)&Cb[(size_t)(mi0 + ty * 4 + r) * N + nj0 + tx * 4] = pk.q;
    }
}

// ---------------- fused: sim = T_h wk_h^T * SCALE -> softmax -> M_h = attn * wv_h (fp32) ----------------
__global__ __launch_bounds__(256) void simsoftm_kernel(const float* __restrict__ T,
                                                       const float* __restrict__ wk,
                                                       const float* __restrict__ wv,
                                                       float* __restrict__ M) {
    int b = blockIdx.x, h = blockIdx.y;

    __shared__ float As[16][68];
    __shared__ float Bs[16][68];
    __shared__ float At[64][68];

    int tid = threadIdx.x;
    int tx = tid & 15, ty = tid >> 4;
    int lrow = tid >> 2, lk = (tid & 3) * 4;
    int ldk = tid >> 4, ldn = (tid & 15) * 4;

    const float* Th  = T + (size_t)b * 512 * C_IN + (size_t)(h * 64) * C_IN;
    const float* wkh = wk + (size_t)(h * 64) * C_IN;
    const float* wvh = wv + (size_t)(h * 64) * C_IN;

    float acc[4][4] = {};
    for (int k0 = 0; k0 < C_IN; k0 += 16) {
        float4 av = *(const float4*)(Th  + (size_t)lrow * C_IN + k0 + lk);
        float4 bv = *(const float4*)(wkh + (size_t)lrow * C_IN + k0 + lk);
        __syncthreads();
        As[lk + 0][lrow] = av.x; As[lk + 1][lrow] = av.y;
        As[lk + 2][lrow] = av.z; As[lk + 3][lrow] = av.w;
        Bs[lk + 0][lrow] = bv.x; Bs[lk + 1][lrow] = bv.y;
        Bs[lk + 2][lrow] = bv.z; Bs[lk + 3][lrow] = bv.w;
        __syncthreads();
#pragma unroll
        for (int kk = 0; kk < 16; kk++) {
            float4 a = *(const float4*)&As[kk][ty * 4];
            float4 bb = *(const float4*)&Bs[kk][tx * 4];
            acc[0][0] += a.x * bb.x; acc[0][1] += a.x * bb.y; acc[0][2] += a.x * bb.z; acc[0][3] += a.x * bb.w;
            acc[1][0] += a.y * bb.x; acc[1][1] += a.y * bb.y; acc[1][2] += a.y * bb.z; acc[1][3] += a.y * bb.w;
            acc[2][0] += a.z * bb.x; acc[2][1] += a.z * bb.y; acc[2][2] += a.z * bb.z; acc[2][3] += a.z * bb.w;
            acc[3][0] += a.w * bb.x; acc[3][1] += a.w * bb.y; acc[3][2] += a.w * bb.z; acc[3][3] += a.w * bb.w;
        }
    }

#pragma unroll
    for (int r = 0; r < 4; r++) {
        float s0 = acc[r][0] * ATT_SCALE, s1 = acc[r][1] * ATT_SCALE;
        float s2 = acc[r][2] * ATT_SCALE, s3 = acc[r][3] * ATT_SCALE;
        float mx = fmaxf(fmaxf(s0, s1), fmaxf(s2, s3));
        mx = fmaxf(mx, __shfl_xor(mx, 1));
        mx = fmaxf(mx, __shfl_xor(mx, 2));
        mx = fmaxf(mx, __shfl_xor(mx, 4));
        mx = fmaxf(mx, __shfl_xor(mx, 8));
        float e0 = __expf(s0 - mx), e1 = __expf(s1 - mx);
        float e2 = __expf(s2 - mx), e3 = __expf(s3 - mx);
        float sum = (e0 + e1) + (e2 + e3);
        sum += __shfl_xor(sum, 1);
        sum += __shfl_xor(sum, 2);
        sum += __shfl_xor(sum, 4);
        sum += __shfl_xor(sum, 8);
        float inv = 1.0f / sum;
        At[tx * 4 + 0][ty * 4 + r] = e0 * inv;
        At[tx * 4 + 1][ty * 4 + r] = e1 * inv;
        At[tx * 4 + 2][ty * 4 + r] = e2 * inv;
        At[tx * 4 + 3][ty * 4 + r] = e3 * inv;
    }

    float* Mb = M + (size_t)b * 512 * C_IN + (size_t)(h * 64) * C_IN;
    for (int nj = 0; nj < C_IN; nj += 64) {
        float acc2[4][4] = {};
        for (int j0 = 0; j0 < 64; j0 += 16) {
            float4 bv = *(const float4*)(wvh + (size_t)(j0 + ldk) * C_IN + nj + ldn);
            __syncthreads();
            *(float4*)&Bs[ldk][ldn] = bv;
            __syncthreads();
#pragma unroll
            for (int kk = 0; kk < 16; kk++) {
                float4 a = *(const float4*)&At[j0 + kk][ty * 4];
                float4 bb = *(const float4*)&Bs[kk][tx * 4];
                acc2[0][0] += a.x * bb.x; acc2[0][1] += a.x * bb.y; acc2[0][2] += a.x * bb.z; acc2[0][3] += a.x * bb.w;
                acc2[1][0] += a.y * bb.x; acc2[1][1] += a.y * bb.y; acc2[1][2] += a.y * bb.z; acc2[1][3] += a.y * bb.w;
                acc2[2][0] += a.z * bb.x; acc2[2][1] += a.z * bb.y; acc2[2][2] += a.z * bb.z; acc2[2][3] += a.z * bb.w;
                acc2[3][0] += a.w * bb.x; acc2[3][1] += a.w * bb.y; acc2[3][2] += a.w * bb.z; acc2[3][3] += a.w * bb.w;
            }
        }
#pragma unroll
        for (int r = 0; r < 4; r++) {
            float4 v = { acc2[r][0], acc2[r][1], acc2[r][2], acc2[r][3] };
            *(float4*)(Mb + (size_t)(ty * 4 + r) * C_IN + nj + tx * 4) = v;
        }
    }
}

// ---------------- out = W*x + bo, bf16 MFMA. grid (256, NB), block 256 (4 waves) ----------------
__global__ __launch_bounds__(256) void final_kernel(const float* __restrict__ x,
                                                    const unsigned short* __restrict__ Wbf,
                                                    const float* __restrict__ bo,
                                                    float* __restrict__ out) {
    int n0 = blockIdx.x * 128;
    int b  = blockIdx.y;

    __shared__ unsigned short Xs[128 * 40];

    int tid  = threadIdx.x;
    int wave = tid >> 6;
    int lane = tid & 63;
    int wm   = (wave & 1) * 96;
    int wn   = (wave >> 1) * 64;
    int lm   = lane & 15, quad = lane >> 4;

    int sn  = tid & 127;
    int skh = (tid >> 7) * 16;

    const float* xsrc = x + (size_t)b * C_IN * S_TOT + n0 + sn;
    const unsigned short* Wb = Wbf + b * C_IN * C_IN;

    f32x4 acc[6][4];
#pragma unroll
    for (int mt = 0; mt < 6; mt++)
#pragma unroll
        for (int nt = 0; nt < 4; nt++) acc[mt][nt] = (f32x4){0.f, 0.f, 0.f, 0.f};

    float pf[16];
#pragma unroll
    for (int j = 0; j < 16; j++) pf[j] = xsrc[(size_t)(skh + j) * S_TOT];

    for (int kc = 0; kc < 6; ++kc) {
        int k0 = kc * 32;
        __syncthreads();
        {
            union { uint4 q; unsigned int u[4]; } pk0, pk1;
#pragma unroll
            for (int j = 0; j < 4; j++) {
                pk0.u[j] = pk_bf16(pf[2 * j],     pf[2 * j + 1]);
                pk1.u[j] = pk_bf16(pf[8 + 2 * j], pf[8 + 2 * j + 1]);
            }
            *(uint4*)&Xs[sn * 40 + skh + 0] = pk0.q;
            *(uint4*)&Xs[sn * 40 + skh + 8] = pk1.q;
        }
        __syncthreads();
        if (kc + 1 < 6) {
            int kn = k0 + 32;
#pragma unroll
            for (int j = 0; j < 16; j++) pf[j] = xsrc[(size_t)(kn + skh + j) * S_TOT];
        }

        short8 afr[6];
#pragma unroll
        for (int mt = 0; mt < 6; mt++)
            afr[mt] = *(const short8*)(Wb + (size_t)(wm + mt * 16 + lm) * C_IN + k0 + quad * 8);
#pragma unroll
        for (int nt = 0; nt < 4; nt++) {
            short8 bfr = *(const short8*)&Xs[(wn + nt * 16 + lm) * 40 + quad * 8];
#pragma unroll
            for (int mt = 0; mt < 6; mt++)
                acc[mt][nt] = __builtin_amdgcn_mfma_f32_16x16x32_bf16(afr[mt], bfr, acc[mt][nt], 0, 0, 0);
        }
    }

#pragma unroll
    for (int mt = 0; mt < 6; mt++) {
#pragma unroll
        for (int r = 0; r < 4; r++) {
            int m = wm + mt * 16 + quad * 4 + r;
            float bias = bo[m];
            float* op = out + ((size_t)b * C_IN + m) * S_TOT + n0;
#pragma unroll
            for (int nt = 0; nt < 4; nt++)
                op[wn + nt * 16 + lm] = acc[mt][nt][r] + bias;
        }
    }
}

extern "C" void kernel_launch(void* const* d_in, const int* in_sizes, int n_in,
                              void* d_out, int out_size, void* d_ws, size_t ws_size,
                              hipStream_t stream) {
    const float* x  = (const float*)d_in[0];
    const float* wq = (const float*)d_in[1];
    const float* wk = (const float*)d_in[2];
    const float* wv = (const float*)d_in[3];
    const float* wo = (const float*)d_in[4];
    const float* bo = (const float*)d_in[5];
    float* out = (float*)d_out;
    float* ws  = (float*)d_ws;

    float* gG = ws + G_OFF;
    float* gT = ws + T_OFF;
    float* gM = ws + M_OFF;
    unsigned short* gWbf = (unsigned short*)(ws + WBF_OFF);
    float* gP = ws + P_OFF;

    hipMemsetAsync(gG, 0, G_SZ * sizeof(float), stream);

    bool bigws = ws_size >= (size_t)(P_OFF + P_SZ) * sizeof(float);
    if (bigws) {
        gram_partial<<<dim3(NSLICE, NB), 512, 0, stream>>>(x, gP);
        gram_reduce<<<dim3(36, 4, NB), 256, 0, stream>>>(gP, gG);
    } else {
        gram_atomic<<<dim3(NSLICE, NB), 512, 0, stream>>>(x, gG);
    }

    // T[b] = wq (512x192) * G_b (192x192)
    gemm64_kernel<<<dim3(8, 3, NB), 256, 0, stream>>>(
        wq, gG, gT, C_IN, C_IN, 0L, (long)(C_IN * C_IN), (long)(512 * C_IN));

    simsoftm_kernel<<<dim3(NB, NH), 256, 0, stream>>>(gT, wk, wv, gM);

    // W[b] = wo (192x512) * M_b (512x192), bf16 packed out
    gemm64bf_kernel<<<dim3(3, 3, NB), 256, 0, stream>>>(
        wo, gM, gWbf, 512, C_IN, 0L, (long)(512 * C_IN), (long)(C_IN * C_IN));

    final_kernel<<<dim3(256, NB), 256, 0, stream>>>(x, gWbf, bo, out);
}